// Round 2
// baseline (285.497 us; speedup 1.0000x reference)
//
#include <hip/hip_runtime.h>

#define N_PTS 1000000
#define H_DIM 200
#define W_DIM 70400
#define FILL_V -9999999.0f

// ---------------------------------------------------------------------------
// Kernel A: per-point MLP (4->18->36->36->1) + bucket by column.
// Bucket entry: .x = value bits, .y = (point_index << 8) | row  (row < 200 < 256)
// Reference scatter is last-write-wins: a point's write survives iff no LATER
// point hits the same (row, col). Resolved in kernel B by comparing indices.
// NOTE: tensor_index arrives as int32 on device (harness converts int64->int32).
// ---------------------------------------------------------------------------
__global__ void __launch_bounds__(256) mlp_scatter_kernel(
    const float* __restrict__ input,        // [4][N]
    const int* __restrict__ tindex,         // [N][2] int32 (row, col)
    const float* __restrict__ w1, const float* __restrict__ b1,
    const float* __restrict__ w2, const float* __restrict__ b2,
    const float* __restrict__ w3, const float* __restrict__ b3,
    const float* __restrict__ w4, const float* __restrict__ b4,
    int* __restrict__ counts,               // [W]
    uint2* __restrict__ list,               // [W][maxk]
    int maxk)
{
    __shared__ float sw1[72], sb1[18];
    __shared__ float sw2[648], sb2[36];
    __shared__ float sw3[1296], sb3[36];
    __shared__ float sw4[36];
    __shared__ float sb4;

    const int t = threadIdx.x;
    for (int k = t; k < 72;   k += 256) sw1[k] = w1[k];
    for (int k = t; k < 18;   k += 256) sb1[k] = b1[k];
    for (int k = t; k < 648;  k += 256) sw2[k] = w2[k];
    for (int k = t; k < 36;   k += 256) sb2[k] = b2[k];
    for (int k = t; k < 1296; k += 256) sw3[k] = w3[k];
    for (int k = t; k < 36;   k += 256) sb3[k] = b3[k];
    for (int k = t; k < 36;   k += 256) sw4[k] = w4[k];
    if (t == 0) sb4 = b4[0];
    __syncthreads();

    // empty-branch check (reference: tensor_index[0,0] == -1 -> no scatter)
    if (tindex[0] == -1) return;

    const int i = blockIdx.x * 256 + t;
    if (i >= N_PTS) return;

    const float x0 = input[0 * N_PTS + i];
    const float x1 = input[1 * N_PTS + i];
    const float x2 = input[2 * N_PTS + i];
    const float x3 = input[3 * N_PTS + i];

    float h1[18];
#pragma unroll
    for (int o = 0; o < 18; ++o) {
        float a = sb1[o];
        a = fmaf(sw1[o * 4 + 0], x0, a);
        a = fmaf(sw1[o * 4 + 1], x1, a);
        a = fmaf(sw1[o * 4 + 2], x2, a);
        a = fmaf(sw1[o * 4 + 3], x3, a);
        h1[o] = fmaxf(a, 0.0f);
    }

    float h2[36];
#pragma unroll
    for (int o = 0; o < 36; ++o) {
        float a = sb2[o];
#pragma unroll
        for (int k = 0; k < 18; ++k) a = fmaf(sw2[o * 18 + k], h1[k], a);
        h2[o] = fmaxf(a, 0.0f);
    }

    float h3[36];
#pragma unroll
    for (int o = 0; o < 36; ++o) {
        float a = sb3[o];
#pragma unroll
        for (int k = 0; k < 36; ++k) a = fmaf(sw3[o * 36 + k], h2[k], a);
        h3[o] = fmaxf(a, 0.0f);
    }

    float v = sb4;
#pragma unroll
    for (int k = 0; k < 36; ++k) v = fmaf(sw4[k], h3[k], v);

    const int hrow = tindex[2 * i];
    const int wcol = tindex[2 * i + 1];

    const int pos = atomicAdd(&counts[wcol], 1);
    if (pos < maxk) {  // statistically never overflows at maxk>=64 (mean 14.2/col)
        uint2 e;
        e.x = __float_as_uint(v);
        e.y = ((unsigned)i << 8) | (unsigned)hrow;
        list[(size_t)wcol * maxk + pos] = e;
    }
}

// ---------------------------------------------------------------------------
// Kernel B: one thread per column. Survivor = no later point with same row.
// Column result = max over survivors, FILL if none. Thread W_DIM writes flag.
// ---------------------------------------------------------------------------
__global__ void __launch_bounds__(256) colmax_kernel(
    const int* __restrict__ tindex,
    const int* __restrict__ counts,
    const uint2* __restrict__ list,
    float* __restrict__ out,
    int maxk)
{
    const int w = blockIdx.x * 256 + threadIdx.x;
    if (w > W_DIM) return;

    const bool empty = (tindex[0] == -1);

    if (w == W_DIM) {            // flag output
        out[w] = empty ? 0.0f : 1.0f;
        return;
    }
    if (empty) { out[w] = FILL_V; return; }

    int c = counts[w];
    if (c > maxk) c = maxk;

    const uint2* le = list + (size_t)w * maxk;
    float m = FILL_V;
    for (int a = 0; a < c; ++a) {
        const uint2 e = le[a];
        const unsigned key = e.y;
        bool alive = true;
        for (int b = 0; b < c; ++b) {
            const unsigned f = le[b].y;
            // same row (low 8 bits) and later point index => this write was overwritten
            if ((((f ^ key) & 0xFFu) == 0u) && (f > key)) { alive = false; break; }
        }
        if (alive) m = fmaxf(m, __uint_as_float(e.x));
    }
    out[w] = m;
}

extern "C" void kernel_launch(void* const* d_in, const int* in_sizes, int n_in,
                              void* d_out, int out_size, void* d_ws, size_t ws_size,
                              hipStream_t stream) {
    const float* input  = (const float*)d_in[0];
    const int*   tindex = (const int*)d_in[1];   // int32 on device per harness contract
    const float* w1 = (const float*)d_in[2];
    const float* b1 = (const float*)d_in[3];
    const float* w2 = (const float*)d_in[4];
    const float* b2 = (const float*)d_in[5];
    const float* w3 = (const float*)d_in[6];
    const float* b3 = (const float*)d_in[7];
    const float* w4 = (const float*)d_in[8];
    const float* b4 = (const float*)d_in[9];
    float* out = (float*)d_out;

    // workspace layout: counts [70400 int] | list [70400 * maxk uint2]
    int*   counts = (int*)d_ws;
    uint2* list   = (uint2*)((char*)d_ws + (size_t)W_DIM * sizeof(int));

    // size maxk to the workspace we actually have (cap 64; need ~36.3 MB for 64)
    size_t avail = (ws_size > (size_t)W_DIM * sizeof(int))
                       ? ws_size - (size_t)W_DIM * sizeof(int) : 0;
    int maxk = (int)(avail / ((size_t)W_DIM * sizeof(uint2)));
    if (maxk > 64) maxk = 64;
    if (maxk < 1)  maxk = 1;   // degenerate; avoids div-by-zero faults

    hipMemsetAsync(counts, 0, (size_t)W_DIM * sizeof(int), stream);

    mlp_scatter_kernel<<<(N_PTS + 255) / 256, 256, 0, stream>>>(
        input, tindex, w1, b1, w2, b2, w3, b3, w4, b4, counts, list, maxk);

    colmax_kernel<<<(W_DIM + 1 + 255) / 256, 256, 0, stream>>>(
        tindex, counts, list, out, maxk);
}

// Round 3
// 221.429 us; speedup vs baseline: 1.2893x; 1.2893x over previous
//
#include <hip/hip_runtime.h>

#define N_PTS 1000000
#define H_DIM 200
#define W_DIM 70400
#define FILL_V -9999999.0f

// ---------------------------------------------------------------------------
// Kernel A: per-point MLP (4->18->36->36->1) + bucket by column.
// Weights staged in LDS with rows padded to 16B alignment so all weight reads
// are ds_read_b128 (531/point instead of 2052 ds_read_b32).
// Bucket list is TRANSPOSED: list[slot][W] so kernel B's loads coalesce.
// Entry: .x = value bits, .y = (point_index << 8) | row   (row < 200 < 256).
// Last-write-wins scatter: a point survives iff no LATER point hit (row,col).
// ---------------------------------------------------------------------------
__global__ void __launch_bounds__(256) mlp_scatter_kernel(
    const float* __restrict__ input,        // [4][N]
    const int* __restrict__ tindex,         // [N][2] int32 (row, col)
    const float* __restrict__ w1, const float* __restrict__ b1,
    const float* __restrict__ w2, const float* __restrict__ b2,
    const float* __restrict__ w3, const float* __restrict__ b3,
    const float* __restrict__ w4, const float* __restrict__ b4,
    int* __restrict__ counts,               // [W]
    uint2* __restrict__ list,               // [maxk][W]  (transposed!)
    int maxk)
{
    __shared__ float4 sw1[18];       // layer1: 18 rows of 4
    __shared__ float4 sw2[36 * 5];   // layer2: 36 rows, 18 padded to 20
    __shared__ float4 sw3[36 * 9];   // layer3: 36 rows of 36
    __shared__ float4 sw4[9];        // layer4: 1 row of 36
    __shared__ float  sb1[18], sb2[36], sb3[36];
    __shared__ float  sb4;

    const int t = threadIdx.x;
    {
        float* p = (float*)sw1;
        for (int k = t; k < 72; k += 256) p[k] = w1[k];
        p = (float*)sw2;
        for (int k = t; k < 720; k += 256) {
            int r = k / 20, c = k % 20;
            p[k] = (c < 18) ? w2[r * 18 + c] : 0.0f;
        }
        p = (float*)sw3;
        for (int k = t; k < 1296; k += 256) p[k] = w3[k];
        p = (float*)sw4;
        for (int k = t; k < 36; k += 256) p[k] = w4[k];
        for (int k = t; k < 18; k += 256) sb1[k] = b1[k];
        for (int k = t; k < 36; k += 256) sb2[k] = b2[k];
        for (int k = t; k < 36; k += 256) sb3[k] = b3[k];
        if (t == 0) sb4 = b4[0];
    }
    __syncthreads();

    // empty-branch (reference: tensor_index[0,0] == -1 -> no scatter)
    if (tindex[0] == -1) return;

    const int i = blockIdx.x * 256 + t;
    if (i >= N_PTS) return;

    const float x0 = input[0 * N_PTS + i];
    const float x1 = input[1 * N_PTS + i];
    const float x2 = input[2 * N_PTS + i];
    const float x3 = input[3 * N_PTS + i];

    float h1[20];
#pragma unroll
    for (int o = 0; o < 18; ++o) {
        const float4 wv = sw1[o];
        float a = sb1[o];
        a = fmaf(wv.x, x0, a); a = fmaf(wv.y, x1, a);
        a = fmaf(wv.z, x2, a); a = fmaf(wv.w, x3, a);
        h1[o] = fmaxf(a, 0.0f);
    }
    h1[18] = 0.0f; h1[19] = 0.0f;

    float h2[36];
#pragma unroll
    for (int o = 0; o < 36; ++o) {
        float a = sb2[o];
#pragma unroll
        for (int q = 0; q < 5; ++q) {
            const float4 wv = sw2[o * 5 + q];
            a = fmaf(wv.x, h1[q * 4 + 0], a);
            a = fmaf(wv.y, h1[q * 4 + 1], a);
            a = fmaf(wv.z, h1[q * 4 + 2], a);
            a = fmaf(wv.w, h1[q * 4 + 3], a);
        }
        h2[o] = fmaxf(a, 0.0f);
    }

    float h3[36];
#pragma unroll
    for (int o = 0; o < 36; ++o) {
        float a = sb3[o];
#pragma unroll
        for (int q = 0; q < 9; ++q) {
            const float4 wv = sw3[o * 9 + q];
            a = fmaf(wv.x, h2[q * 4 + 0], a);
            a = fmaf(wv.y, h2[q * 4 + 1], a);
            a = fmaf(wv.z, h2[q * 4 + 2], a);
            a = fmaf(wv.w, h2[q * 4 + 3], a);
        }
        h3[o] = fmaxf(a, 0.0f);
    }

    float v = sb4;
#pragma unroll
    for (int q = 0; q < 9; ++q) {
        const float4 wv = sw4[q];
        v = fmaf(wv.x, h3[q * 4 + 0], v);
        v = fmaf(wv.y, h3[q * 4 + 1], v);
        v = fmaf(wv.z, h3[q * 4 + 2], v);
        v = fmaf(wv.w, h3[q * 4 + 3], v);
    }

    const int2 hw = ((const int2*)tindex)[i];   // (row, col)
    const int pos = atomicAdd(&counts[hw.y], 1);
    if (pos < maxk) {   // never overflows statistically at maxk>=64 (mean 14.2/col)
        uint2 e;
        e.x = __float_as_uint(v);
        e.y = ((unsigned)i << 8) | (unsigned)hw.x;
        list[(size_t)pos * W_DIM + hw.y] = e;
    }
}

// ---------------------------------------------------------------------------
// Kernel B: block = (64,4). Column w = blk*64+lane; 4 slot-phases (y) split
// the outer survivor loop. Loads list[a*W+w] -> fully coalesced; O(c^2) inner
// re-reads hit L1. Partial maxes reduced via LDS. Thread (0,0) of block 0
// writes the flag.
// ---------------------------------------------------------------------------
__global__ void __launch_bounds__(256) colmax_kernel(
    const int* __restrict__ tindex,
    const int* __restrict__ counts,
    const uint2* __restrict__ list,
    float* __restrict__ out,
    int maxk)
{
    __shared__ float red[4][64];
    const int lane = threadIdx.x;       // 0..63
    const int y    = threadIdx.y;       // 0..3
    const int w    = blockIdx.x * 64 + lane;

    const bool empty = (tindex[0] == -1);

    float m = FILL_V;
    if (w < W_DIM && !empty) {
        int c = counts[w];
        if (c > maxk) c = maxk;
        for (int a = y; a < c; a += 4) {
            const uint2 e = list[(size_t)a * W_DIM + w];
            const unsigned key = e.y;
            bool alive = true;
            for (int b = 0; b < c; ++b) {
                const unsigned f = list[(size_t)b * W_DIM + w].y;
                // same row (low 8 bits) and later point index => overwritten
                if ((((f ^ key) & 0xFFu) == 0u) && (f > key)) { alive = false; break; }
            }
            if (alive) m = fmaxf(m, __uint_as_float(e.x));
        }
    }
    red[y][lane] = m;
    __syncthreads();

    if (y == 0 && w < W_DIM) {
        float r = fmaxf(fmaxf(red[0][lane], red[1][lane]),
                        fmaxf(red[2][lane], red[3][lane]));
        out[w] = r;
    }
    if (blockIdx.x == 0 && lane == 0 && y == 0)
        out[W_DIM] = empty ? 0.0f : 1.0f;
}

extern "C" void kernel_launch(void* const* d_in, const int* in_sizes, int n_in,
                              void* d_out, int out_size, void* d_ws, size_t ws_size,
                              hipStream_t stream) {
    const float* input  = (const float*)d_in[0];
    const int*   tindex = (const int*)d_in[1];   // int32 on device
    const float* w1 = (const float*)d_in[2];
    const float* b1 = (const float*)d_in[3];
    const float* w2 = (const float*)d_in[4];
    const float* b2 = (const float*)d_in[5];
    const float* w3 = (const float*)d_in[6];
    const float* b3 = (const float*)d_in[7];
    const float* w4 = (const float*)d_in[8];
    const float* b4 = (const float*)d_in[9];
    float* out = (float*)d_out;

    // workspace: counts [70400 int] | list [maxk][70400] uint2 (transposed)
    int*   counts = (int*)d_ws;
    uint2* list   = (uint2*)((char*)d_ws + (size_t)W_DIM * sizeof(int));

    size_t avail = (ws_size > (size_t)W_DIM * sizeof(int))
                       ? ws_size - (size_t)W_DIM * sizeof(int) : 0;
    int maxk = (int)(avail / ((size_t)W_DIM * sizeof(uint2)));
    if (maxk > 64) maxk = 64;
    if (maxk < 1)  maxk = 1;

    hipMemsetAsync(counts, 0, (size_t)W_DIM * sizeof(int), stream);

    mlp_scatter_kernel<<<(N_PTS + 255) / 256, 256, 0, stream>>>(
        input, tindex, w1, b1, w2, b2, w3, b3, w4, b4, counts, list, maxk);

    colmax_kernel<<<(W_DIM + 63) / 64, dim3(64, 4), 0, stream>>>(
        tindex, counts, list, out, maxk);
}

// Round 4
// 201.102 us; speedup vs baseline: 1.4197x; 1.1011x over previous
//
#include <hip/hip_runtime.h>

#define N_PTS 1000000
#define H_DIM 200
#define W_DIM 70400
#define FILL_V -9999999.0f

// ---------------------------------------------------------------------------
// Kernel A: per-point MLP (4->18->36->36->1) + bucket by column.
// Weights staged in LDS, rows padded to 16B so reads are ds_read_b128
// (uniform address -> broadcast, conflict-free).
// __launch_bounds__(256,4): 128-VGPR budget so h1/h2/h3 (~92 floats live)
// stay in real VGPRs -- R2's build allocated 72 VGPRs + ~150 AGPR spill slots
// (occupancy 29% at "72" VGPRs) and burned ~34us in v_accvgpr traffic.
// List entry: .x = value bits, .y = (point_index << 8) | row  (row<200<256).
// Last-write-wins scatter: point survives iff no LATER point hit (row,col).
// ---------------------------------------------------------------------------
__global__ void __launch_bounds__(256, 4) mlp_scatter_kernel(
    const float* __restrict__ input,        // [4][N]
    const int* __restrict__ tindex,         // [N][2] int32 (row, col)
    const float* __restrict__ w1, const float* __restrict__ b1,
    const float* __restrict__ w2, const float* __restrict__ b2,
    const float* __restrict__ w3, const float* __restrict__ b3,
    const float* __restrict__ w4, const float* __restrict__ b4,
    int* __restrict__ counts,               // [W]
    uint2* __restrict__ list,               // [W][maxk] row-major per column
    int maxk)
{
    __shared__ float4 sw1[18];       // layer1: 18 rows of 4
    __shared__ float4 sw2[36 * 5];   // layer2: 36 rows, 18 padded to 20
    __shared__ float4 sw3[36 * 9];   // layer3: 36 rows of 36
    __shared__ float4 sw4[9];        // layer4: 1 row of 36
    __shared__ float  sb1[18], sb2[36], sb3[36];
    __shared__ float  sb4;

    const int t = threadIdx.x;
    {
        float* p = (float*)sw1;
        for (int k = t; k < 72; k += 256) p[k] = w1[k];
        p = (float*)sw2;
        for (int k = t; k < 720; k += 256) {
            int r = k / 20, c = k % 20;
            p[k] = (c < 18) ? w2[r * 18 + c] : 0.0f;
        }
        p = (float*)sw3;
        for (int k = t; k < 1296; k += 256) p[k] = w3[k];
        p = (float*)sw4;
        for (int k = t; k < 36; k += 256) p[k] = w4[k];
        for (int k = t; k < 18; k += 256) sb1[k] = b1[k];
        for (int k = t; k < 36; k += 256) sb2[k] = b2[k];
        for (int k = t; k < 36; k += 256) sb3[k] = b3[k];
        if (t == 0) sb4 = b4[0];
    }
    __syncthreads();

    // empty-branch (reference: tensor_index[0,0] == -1 -> no scatter)
    if (tindex[0] == -1) return;

    const int i = blockIdx.x * 256 + t;
    if (i >= N_PTS) return;

    const float x0 = input[0 * N_PTS + i];
    const float x1 = input[1 * N_PTS + i];
    const float x2 = input[2 * N_PTS + i];
    const float x3 = input[3 * N_PTS + i];

    float h1[20];
#pragma unroll
    for (int o = 0; o < 18; ++o) {
        const float4 wv = sw1[o];
        float a = sb1[o];
        a = fmaf(wv.x, x0, a); a = fmaf(wv.y, x1, a);
        a = fmaf(wv.z, x2, a); a = fmaf(wv.w, x3, a);
        h1[o] = fmaxf(a, 0.0f);
    }
    h1[18] = 0.0f; h1[19] = 0.0f;

    float h2[36];
#pragma unroll
    for (int o = 0; o < 36; ++o) {
        float a = sb2[o];
#pragma unroll
        for (int q = 0; q < 5; ++q) {
            const float4 wv = sw2[o * 5 + q];
            a = fmaf(wv.x, h1[q * 4 + 0], a);
            a = fmaf(wv.y, h1[q * 4 + 1], a);
            a = fmaf(wv.z, h1[q * 4 + 2], a);
            a = fmaf(wv.w, h1[q * 4 + 3], a);
        }
        h2[o] = fmaxf(a, 0.0f);
    }

    float h3[36];
#pragma unroll
    for (int o = 0; o < 36; ++o) {
        float a = sb3[o];
#pragma unroll
        for (int q = 0; q < 9; ++q) {
            const float4 wv = sw3[o * 9 + q];
            a = fmaf(wv.x, h2[q * 4 + 0], a);
            a = fmaf(wv.y, h2[q * 4 + 1], a);
            a = fmaf(wv.z, h2[q * 4 + 2], a);
            a = fmaf(wv.w, h2[q * 4 + 3], a);
        }
        h3[o] = fmaxf(a, 0.0f);
    }

    float v = sb4;
#pragma unroll
    for (int q = 0; q < 9; ++q) {
        const float4 wv = sw4[q];
        v = fmaf(wv.x, h3[q * 4 + 0], v);
        v = fmaf(wv.y, h3[q * 4 + 1], v);
        v = fmaf(wv.z, h3[q * 4 + 2], v);
        v = fmaf(wv.w, h3[q * 4 + 3], v);
    }

    const int2 hw = ((const int2*)tindex)[i];   // (row, col)
    const int pos = atomicAdd(&counts[hw.y], 1);
    if (pos < maxk) {   // never overflows statistically at maxk>=64 (mean 14.2/col)
        uint2 e;
        e.x = __float_as_uint(v);
        e.y = ((unsigned)i << 8) | (unsigned)hw.x;
        list[(size_t)hw.y * maxk + pos] = e;
    }
}

// ---------------------------------------------------------------------------
// Kernel B: ONE WAVE PER COLUMN. Lane a holds slot a (coalesced 512B load per
// wave). Dedup: broadcast each occupied slot's key via __shfl; a lane dies if
// a later point (higher index) hit the same row. Wave max-reduce survivors.
// 70400 waves -> deep latency hiding (vs 1100 waves in R1's thread-per-col).
// ---------------------------------------------------------------------------
__global__ void __launch_bounds__(256) colmax_kernel(
    const int* __restrict__ tindex,
    const int* __restrict__ counts,
    const uint2* __restrict__ list,
    float* __restrict__ out,
    int maxk)
{
    const int lane = threadIdx.x & 63;
    const int w    = (blockIdx.x * 256 + threadIdx.x) >> 6;   // column id

    const bool empty = (tindex[0] == -1);

    if (blockIdx.x == 0 && threadIdx.x == 0)
        out[W_DIM] = empty ? 0.0f : 1.0f;    // flag output

    if (w >= W_DIM) return;

    if (empty) {
        if (lane == 0) out[w] = FILL_V;
        return;
    }

    int c = counts[w];          // uniform address across wave -> broadcast
    if (c > maxk) c = maxk;

    uint2 e = make_uint2(0u, 0u);
    bool alive = (lane < c);
    if (alive) e = list[(size_t)w * maxk + lane];
    const unsigned key = e.y;

    for (int b = 0; b < c; ++b) {
        const unsigned fb = __shfl(key, b, 64);
        // same row (low 8 bits) and later point index => this write overwritten
        if (alive && (((fb ^ key) & 0xFFu) == 0u) && (fb > key)) alive = false;
    }

    float v = alive ? __uint_as_float(e.x) : FILL_V;
#pragma unroll
    for (int off = 32; off > 0; off >>= 1)
        v = fmaxf(v, __shfl_down(v, off, 64));

    if (lane == 0) out[w] = v;
}

extern "C" void kernel_launch(void* const* d_in, const int* in_sizes, int n_in,
                              void* d_out, int out_size, void* d_ws, size_t ws_size,
                              hipStream_t stream) {
    const float* input  = (const float*)d_in[0];
    const int*   tindex = (const int*)d_in[1];   // int32 on device
    const float* w1 = (const float*)d_in[2];
    const float* b1 = (const float*)d_in[3];
    const float* w2 = (const float*)d_in[4];
    const float* b2 = (const float*)d_in[5];
    const float* w3 = (const float*)d_in[6];
    const float* b3 = (const float*)d_in[7];
    const float* w4 = (const float*)d_in[8];
    const float* b4 = (const float*)d_in[9];
    float* out = (float*)d_out;

    // workspace: counts [70400 int] | list [70400][maxk] uint2
    int*   counts = (int*)d_ws;
    uint2* list   = (uint2*)((char*)d_ws + (size_t)W_DIM * sizeof(int));

    size_t avail = (ws_size > (size_t)W_DIM * sizeof(int))
                       ? ws_size - (size_t)W_DIM * sizeof(int) : 0;
    int maxk = (int)(avail / ((size_t)W_DIM * sizeof(uint2)));
    if (maxk > 64) maxk = 64;
    if (maxk < 1)  maxk = 1;

    hipMemsetAsync(counts, 0, (size_t)W_DIM * sizeof(int), stream);

    mlp_scatter_kernel<<<(N_PTS + 255) / 256, 256, 0, stream>>>(
        input, tindex, w1, b1, w2, b2, w3, b3, w4, b4, counts, list, maxk);

    // one wave per column: 70400 waves, 4 waves/block
    colmax_kernel<<<(W_DIM * 64 + 255) / 256, 256, 0, stream>>>(
        tindex, counts, list, out, maxk);
}